// Round 12
// baseline (561.971 us; speedup 1.0000x reference)
//
#include <hip/hip_runtime.h>

#define N_TOK 262144
#define LATD  128
#define DIMD  256

using f32x4  = __attribute__((ext_vector_type(4)))  float;
using f32x16 = __attribute__((ext_vector_type(16))) float;
using f16x8  = __attribute__((ext_vector_type(8)))  _Float16;
using f16x2  = __attribute__((ext_vector_type(2)))  _Float16;

// ---------------- workspace layout (32-bit word offsets) ----------------
#define W_PACK_SYN 0         // 65536 f16 (32768 words)
#define W_PACK_SEM 32768     // 131072 f16 (65536 words)
#define W_CBN_SYN  98304     // 64  f32 ||cb||^2
#define W_CBN_SEM  98368     // 128 f32
#define W_IDX_SYN  98496     // 262144 i32
#define W_IDX_SEM  360640    // 262144 i32
#define W_CNT_SYN  622784    // 64  i32
#define W_CNT_SEM  622848    // 128 i32
#define W_EMB_SYN  622976    // 64x256 f32
#define W_EMB_SEM  639360    // 128x256 f32
#define W_MRK_SYN  672128    // 64x64 i32
#define W_MRK_SEM  676224    // 128x128 i32
#define W_LOSSP_SYN 692612   // 2048 f32 per-block loss partials
#define W_LOSSP_SEM 700804   // 2048 f32
#define W_ZERO_BEG 622784
#define W_ZERO_END 692612

// ---------------- output layout (float offsets) ----------------
#define OFF_ZQ_SYN  0LL
#define OFF_ZQ_SEM  67108864LL
#define OFF_LOSS    134217728LL
#define OFF_IDX_SYN 134217729LL
#define OFF_IDX_SEM 134479873LL
#define OFF_CB_SYN  134742017LL
#define OFF_CL_SYN  134758401LL
#define OFF_AVG_SYN 134758465LL
#define OFF_ADJ_SYN 134774849LL
#define OFF_CB_SEM  134778945LL
#define OFF_CL_SEM  134811713LL
#define OFF_AVG_SEM 134811841LL
#define OFF_ADJ_SEM 134844609LL

__device__ inline void gload16(const void* g, void* l) {
  __builtin_amdgcn_global_load_lds(
      (const __attribute__((address_space(1))) unsigned int*)g,
      (__attribute__((address_space(3))) unsigned int*)l, 16, 0, 0);
}

// ==================== prep: zero + pack(syn,sem) + norms ====================
template <int K>
__device__ void prep_pack_body(int bid2, const float* __restrict__ cb,
                               const float* __restrict__ W, _Float16* __restrict__ pack) {
  constexpr int NCT = 2 * K / 32;
  constexpr int PER_KT = NCT * 512;
  int t = bid2 * 256 + threadIdx.x;
  int kt = t / PER_KT;
  int r  = t - kt * PER_KT;
  int l  = (r >> 3) & 63;
  int e  = r & 7;
  int ct = r >> 9;
  int j   = kt * 16 + (l >> 5) * 8 + e;
  int col = ct * 32 + (l & 31);
  float x = (col < K) ? cb[col * DIMD + j] : W[j * K + (col - K)];
  _Float16 h = (_Float16)x;
  _Float16 lo = (_Float16)(x - (float)h);
  pack[(size_t)kt * 2 * PER_KT + r]          = h;
  pack[(size_t)kt * 2 * PER_KT + PER_KT + r] = lo;
}

__global__ __launch_bounds__(256) void k_prep(
    const float* __restrict__ cbs, const float* __restrict__ cbm,
    const float* __restrict__ Wsy, const float* __restrict__ Wse,
    float* __restrict__ ws, _Float16* __restrict__ packs, _Float16* __restrict__ packm) {
  __shared__ float red[256];
  const int bid = blockIdx.x, tid = threadIdx.x;
  if (bid < 273) {
    int idx = W_ZERO_BEG + bid * 256 + tid;
    if (idx < W_ZERO_END) ws[idx] = 0.0f;
  } else if (bid < 401) {
    prep_pack_body<64>(bid - 273, cbs, Wsy, packs);
  } else if (bid < 657) {
    prep_pack_body<128>(bid - 401, cbm, Wse, packm);
  } else {
    int k = bid - 657;
    const float* src; float* dst;
    if (k < 64) { src = cbs + (size_t)k * DIMD; dst = ws + W_CBN_SYN + k; }
    else        { src = cbm + (size_t)(k - 64) * DIMD; dst = ws + W_CBN_SEM + (k - 64); }
    float v = src[tid];
    red[tid] = v * v;
    __syncthreads();
    for (int s = 128; s > 0; s >>= 1) {
      if (tid < s) red[tid] += red[tid + s];
      __syncthreads();
    }
    if (tid == 0) *dst = red[0];
  }
}

// ==================== pass A: paired-kt LDS pack staging + z reg prefetch ====================
// Wave owns 32 tokens x all 2K entry rows.  Pack chunks staged in PAIRS
// (2 kt per buffer, double-buffered) -> one barrier per pair (8 total);
// z register-prefetched one full pair ahead (~2x compute window >= HBM lat).
// Numerics identical to the round-10 kernel.
template <int K>
__global__ __launch_bounds__(256, 2) void k_passA(
    const float* __restrict__ zre, const float* __restrict__ zim,
    const _Float16* __restrict__ pack, const float* __restrict__ cbn,
    const float* __restrict__ cb,  const float* __restrict__ bvec,
    const float* __restrict__ adj, const int* __restrict__ prev,
    float* __restrict__ zq_out, float* __restrict__ idxf_out,
    int* __restrict__ idxi_ws, int* __restrict__ mark_ws,
    float* __restrict__ lossp) {
  constexpr int NCT = K / 16;             // 32-row tiles: 4 / 8
  constexpr int NH  = K / 32;             // 2 / 4
  constexpr int PER_KT = NCT * 512;       // f16 per hi (or lo) chunk
  constexpr int CHUNK = 2 * PER_KT;       // f16 per kt (hi+lo): 4096 / 8192
  constexpr int PBYTES = CHUNK * 2;       // bytes per kt chunk: 8 KB / 16 KB
  constexpr int SIT2 = CHUNK / 1024;      // 16B iters/thread per PAIR: 4 / 8
  __shared__ __align__(16) char smem[4 * PBYTES];  // 2 bufs x 2 chunks
  __shared__ float wred[4];

  const int tid  = threadIdx.x;
  const int lane = tid & 63;
  const int wv   = tid >> 6;
  const int kg   = lane >> 5;
  const int j    = lane & 31;
  const int t0   = blockIdx.x * 128 + wv * 32;
  const int gt   = t0 + j;

  auto stage = [&](int kt2) {           // stage chunk pair (2*kt2, 2*kt2+1)
    const _Float16* src = pack + (size_t)kt2 * 2 * CHUNK;
    char* dst = smem + (kt2 & 1) * 2 * PBYTES;
#pragma unroll
    for (int i = 0; i < SIT2; ++i)
      gload16(src + (size_t)(i * 256 + tid) * 8,
              dst + ((i * 256 + (tid & 192)) << 4));
  };

  f32x16 acc[NCT];
#pragma unroll
  for (int t = 0; t < NCT; ++t)
#pragma unroll
    for (int r = 0; r < 16; ++r) acc[t][r] = 0.0f;
  float zn = 0.0f;

  stage(0);
  f32x4 va0, va1, vb0, vb1, na0, na1, nb0, nb1;
  {
    const float* zp = zre + (size_t)gt * LATD + kg * 8;
    va0 = *(const f32x4*)zp;
    va1 = *(const f32x4*)(zp + 4);
    vb0 = *(const f32x4*)(zp + 16);
    vb1 = *(const f32x4*)(zp + 20);
  }
  for (int kt2 = 0; kt2 < 8; ++kt2) {
    __syncthreads();                    // pair(kt2) resident; buf^1 free
    if (kt2 + 1 < 8) {
      stage(kt2 + 1);
      const int ka = 2 * kt2 + 2;
      const float* zsa = (ka < 8) ? zre : zim;
      const float* zpa = zsa + (size_t)gt * LATD + (ka & 7) * 16 + kg * 8;
      na0 = *(const f32x4*)zpa;
      na1 = *(const f32x4*)(zpa + 4);
      const int kb = ka + 1;
      const float* zsb = (kb < 8) ? zre : zim;
      const float* zpb = zsb + (size_t)gt * LATD + (kb & 7) * 16 + kg * 8;
      nb0 = *(const f32x4*)zpb;
      nb1 = *(const f32x4*)(zpb + 4);
    }
#pragma unroll
    for (int s = 0; s < 2; ++s) {
      f32x4 v0 = s ? vb0 : va0;
      f32x4 v1 = s ? vb1 : va1;
      f16x8 Bh, Bl;
#pragma unroll
      for (int e = 0; e < 4; ++e) {
        _Float16 h0 = (_Float16)v0[e];
        Bh[e] = h0;       Bl[e] = (_Float16)(v0[e] - (float)h0);
        _Float16 h1 = (_Float16)v1[e];
        Bh[e + 4] = h1;   Bl[e + 4] = (_Float16)(v1[e] - (float)h1);
        zn += v0[e] * v0[e];
        zn += v1[e] * v1[e];
      }
      const _Float16* Bp = (const _Float16*)(smem + (kt2 & 1) * 2 * PBYTES) + s * CHUNK;
#pragma unroll
      for (int t = 0; t < NCT; ++t) {
        f16x8 Ah = *(const f16x8*)(Bp + (size_t)t * 512 + lane * 8);
        f16x8 Al = *(const f16x8*)(Bp + PER_KT + (size_t)t * 512 + lane * 8);
        acc[t] = __builtin_amdgcn_mfma_f32_32x32x16_f16(Ah, Bh, acc[t], 0, 0, 0);
        acc[t] = __builtin_amdgcn_mfma_f32_32x32x16_f16(Ah, Bl, acc[t], 0, 0, 0);
        acc[t] = __builtin_amdgcn_mfma_f32_32x32x16_f16(Al, Bh, acc[t], 0, 0, 0);
      }
    }
    va0 = na0; va1 = na1; vb0 = nb0; vb1 = nb1;
  }

  const int pv = prev[gt];

  // softmax over logit tiles (in-register)
  float mx = -1e30f;
#pragma unroll
  for (int t = 0; t < NH; ++t)
#pragma unroll
    for (int q = 0; q < 4; ++q) {
      f32x4 bv4 = *(const f32x4*)&bvec[t * 32 + 8 * q + 4 * kg];
#pragma unroll
      for (int b = 0; b < 4; ++b) {
        acc[NH + t][4 * q + b] += bv4[b];
        mx = fmaxf(mx, acc[NH + t][4 * q + b]);
      }
    }
  mx = fmaxf(mx, __shfl_xor(mx, 32));
  float es = 0.0f;
#pragma unroll
  for (int t = 0; t < NH; ++t)
#pragma unroll
    for (int r = 0; r < 16; ++r) {
      acc[NH + t][r] = __expf(acc[NH + t][r] - mx);
      es += acc[NH + t][r];
    }
  es += __shfl_xor(es, 32);
  const float inv = 1.0f / es;

  // biased argmin as argmax of sc = dot - cbn/2 + 0.4 sg + p
  const float* adjrow = adj + (size_t)pv * K;
  float best = -1e30f; int bidx = 0; float bdot = 0.0f;
#pragma unroll
  for (int t = 0; t < NH; ++t)
#pragma unroll
    for (int q = 0; q < 4; ++q) {
      const int e0 = t * 32 + 8 * q + 4 * kg;
      f32x4 cb4v = *(const f32x4*)&cbn[e0];
      f32x4 ad4  = *(const f32x4*)&adjrow[e0];
#pragma unroll
      for (int b = 0; b < 4; ++b) {
        int r = 4 * q + b;
        float dot = acc[t][r];
        float sg  = 1.0f / (1.0f + __expf(-ad4[b]));
        float sc  = dot - 0.5f * cb4v[b] + 0.4f * sg + acc[NH + t][r] * inv;
        int   e   = e0 + b;
        if (sc > best || (sc == best && e < bidx)) {
          best = sc; bidx = e; bdot = dot;
        }
      }
    }
  {
    float ob = __shfl_xor(best, 32);
    int   oi = __shfl_xor(bidx, 32);
    float od = __shfl_xor(bdot, 32);
    if (ob > best || (ob == best && oi < bidx)) { best = ob; bidx = oi; bdot = od; }
  }
  const float znf = zn + __shfl_xor(zn, 32);

  float lj = 0.0f;
  if (lane < 32) {
    idxf_out[gt] = (float)bidx;
    idxi_ws[gt]  = bidx;
    mark_ws[pv * K + bidx] = 1;
    lj = cbn[bidx] + znf - 2.0f * bdot;
  }
#pragma unroll
  for (int off = 32; off; off >>= 1) lj += __shfl_xor(lj, off);
  if (lane == 0) wred[wv] = lj;

  // zq gather-write
  const float4* cb4p = (const float4*)cb;
  float4* zq4 = (float4*)zq_out;
#pragma unroll 4
  for (int i = 0; i < 32; ++i) {
    int bi_i = __shfl(bidx, i);
    zq4[(size_t)(t0 + i) * 64 + lane] = cb4p[(size_t)bi_i * 64 + lane];
  }
  __syncthreads();
  if (tid == 0) lossp[blockIdx.x] = wred[0] + wred[1] + wred[2] + wred[3];
}

// ==================== pass B (merged, interleaved, dbuf zT) ====================
template <int K>
__device__ void passB_body(int fid,
    const float* __restrict__ zre, const float* __restrict__ zim,
    const int* __restrict__ idxi,
    float* __restrict__ emb_ws, int* __restrict__ cnt_ws,
    int* idxl, int* cntl, unsigned short* zT) {
  constexpr int TPB  = 2048;
  constexpr int CH   = 128;
  constexpr int NCT2 = (K == 64) ? 1 : 2;
  const int tid  = threadIdx.x;
  const int lane = tid & 63, wv = tid >> 6;
  const int cg    = fid & 3;
  const int chunk = fid >> 2;
  const int tbase = chunk * TPB;

  if (tid < K) cntl[tid] = 0;
  __syncthreads();
#pragma unroll
  for (int i = 0; i < TPB / 256; ++i) {
    int id = idxi[tbase + i * 256 + tid];
    idxl[i * 256 + tid] = id;
    if (cg == 0) atomicAdd(&cntl[id], 1);
  }
  __syncthreads();
  if (cg == 0 && tid < K) atomicAdd(&cnt_ws[tid], cntl[tid]);

  const int rt  = (K == 64) ? (wv & 1) : wv;
  const int ct0 = (K == 64) ? (wv >> 1) : 0;
  const int krow = rt * 32 + (lane & 31);
  const int kg   = lane >> 5;
  const float* zsrc = (cg < 2) ? zre : zim;
  const int cbase = (cg & 1) * 64;

  f32x16 acc[NCT2];
#pragma unroll
  for (int c = 0; c < NCT2; ++c)
#pragma unroll
    for (int r = 0; r < 16; ++r) acc[c][r] = 0.0f;

  const int sq = tid & 15;
  const int sp = tid >> 4;

  auto stage = [&](int sc) {
    unsigned short* zb = zT + (sc & 1) * 8192;
#pragma unroll
    for (int it = 0; it < 4; ++it) {
      int p = sp + it * 16;
      int t = sc * CH + 2 * p;
      const float* zr = zsrc + (size_t)(tbase + t) * LATD + cbase + 4 * sq;
      f32x4 a = *(const f32x4*)zr;
      f32x4 b = *(const f32x4*)(zr + LATD);
#pragma unroll
      for (int c4 = 0; c4 < 4; ++c4) {
        int c = 4 * sq + c4;
        f16x2 pr;
        pr[0] = (_Float16)a[c4];
        pr[1] = (_Float16)b[c4];
        int byte = c * 256 + ((4 * p) ^ ((c & 7) << 4));
        *(f16x2*)((char*)zb + byte) = pr;
      }
    }
  };

  stage(0);
  for (int sc = 0; sc < TPB / CH; ++sc) {
    __syncthreads();
    if (sc + 1 < TPB / CH) stage(sc + 1);
    const unsigned short* zb = zT + (sc & 1) * 8192;
#pragma unroll
    for (int st = 0; st < 8; ++st) {
      const int tloc = sc * CH + st * 16 + kg * 8;
      f16x8 Af;
#pragma unroll
      for (int e = 0; e < 8; ++e)
        Af[e] = (idxl[tloc + e] == krow) ? (_Float16)1.0f : (_Float16)0.0f;
#pragma unroll
      for (int c = 0; c < NCT2; ++c) {
        int col = (ct0 + c) * 32 + (lane & 31);
        int byte = col * 256 + ((st * 32 + kg * 16) ^ ((col & 7) << 4));
        f16x8 Bf = *(const f16x8*)((const char*)zb + byte);
        acc[c] = __builtin_amdgcn_mfma_f32_32x32x16_f16(Af, Bf, acc[c], 0, 0, 0);
      }
    }
  }
#pragma unroll
  for (int c = 0; c < NCT2; ++c)
#pragma unroll
    for (int r = 0; r < 16; ++r) {
      int row = rt * 32 + (r & 3) + 8 * (r >> 2) + 4 * (lane >> 5);
      int col = cg * 64 + (ct0 + c) * 32 + (lane & 31);
      atomicAdd(&emb_ws[row * DIMD + col], acc[c][r]);
    }
}

__global__ __launch_bounds__(256) void k_passB_all(
    const float* __restrict__ zfre, const float* __restrict__ zfim,
    const float* __restrict__ zsre, const float* __restrict__ zsim,
    const int* __restrict__ idxis, const int* __restrict__ idxim,
    float* __restrict__ embs, float* __restrict__ embm,
    int* __restrict__ cnts, int* __restrict__ cntm) {
  __shared__ int idxl[2048];
  __shared__ int cntl[128];
  __shared__ __align__(16) unsigned short zT[2 * 8192];
  const int fid = blockIdx.x >> 1;
  if ((blockIdx.x & 1) == 0)
    passB_body<64>(fid, zfre, zfim, idxis, embs, cnts, idxl, cntl, zT);
  else
    passB_body<128>(fid, zsre, zsim, idxim, embm, cntm, idxl, cntl, zT);
}

// ==================== finalize (merged) ====================
__global__ __launch_bounds__(256) void k_fin(
    const float* __restrict__ ws, const float* __restrict__ clsi, const float* __restrict__ clmi,
    const float* __restrict__ avgs, const float* __restrict__ avgm,
    const float* __restrict__ adjs, const float* __restrict__ adjm,
    float* __restrict__ o_loss, float* __restrict__ o_cl_syn, float* __restrict__ o_cl_sem,
    float* __restrict__ o_cb_syn, float* __restrict__ o_avg_syn, float* __restrict__ o_adj_syn,
    float* __restrict__ o_cb_sem, float* __restrict__ o_avg_sem, float* __restrict__ o_adj_sem) {
  __shared__ float sred[256];
  const int* wsi = (const int*)ws;
  const int bid = blockIdx.x, tid = threadIdx.x;
  if (bid == 0) {
    float s = 0.0f;
    for (int i = tid; i < 2048; i += 256) s += ws[W_LOSSP_SYN + i];
    for (int i = tid; i < 2048; i += 256) s += ws[W_LOSSP_SEM + i];
    sred[tid] = s;
    __syncthreads();
    for (int st = 128; st > 0; st >>= 1) {
      if (tid < st) sred[tid] += sred[tid + st];
      __syncthreads();
    }
    if (tid < 64)
      o_cl_syn[tid] = clsi[tid] * 0.99f + 0.01f * (float)wsi[W_CNT_SYN + tid];
    if (tid < 128)
      o_cl_sem[tid] = clmi[tid] * 0.99f + 0.01f * (float)wsi[W_CNT_SEM + tid];
    if (tid == 0)
      *o_loss = 1.25f * sred[0] / ((float)N_TOK * 256.0f);
    return;
  }
  const int e = (bid - 1) * 256 + tid;
  float n = 0.0f;
  if (e < 49152) {
    const bool syn = e < 16384;
    const int KK = syn ? 64 : 128;
    const float* clp = syn ? clsi : clmi;
    const int cntoff = syn ? W_CNT_SYN : W_CNT_SEM;
    float v = 0.0f;
    if (tid < KK) v = clp[tid] * 0.99f + 0.01f * (float)wsi[cntoff + tid];
    sred[tid] = v;
    __syncthreads();
    for (int st = 128; st > 0; st >>= 1) {
      if (tid < st) sred[tid] += sred[tid + st];
      __syncthreads();
    }
    n = sred[0];
  }
  if (e < 16384) {
    int k = e >> 8;
    float av = avgs[e] * 0.99f + 0.01f * ws[W_EMB_SYN + e];
    o_avg_syn[e] = av;
    float cnt = (float)wsi[W_CNT_SYN + k];
    float cl  = clsi[k] * 0.99f + 0.01f * cnt;
    float cs  = (cl + 1e-6f) / (n + (float)(64 * 1e-6)) * n;
    o_cb_syn[e] = av / cs;
  } else if (e < 49152) {
    int e2 = e - 16384;
    int k = e2 >> 8;
    float av = avgm[e2] * 0.99f + 0.01f * ws[W_EMB_SEM + e2];
    o_avg_sem[e2] = av;
    float cnt = (float)wsi[W_CNT_SEM + k];
    float cl  = clmi[k] * 0.99f + 0.01f * cnt;
    float cs  = (cl + 1e-6f) / (n + (float)(128 * 1e-6)) * n;
    o_cb_sem[e2] = av / cs;
  } else if (e < 53248) {
    int a = e - 49152;
    float old = adjs[a];
    o_adj_syn[a] = wsi[W_MRK_SYN + a] ? old * 0.995f + 1.0f : old;
  } else if (e < 69632) {
    int a = e - 53248;
    float old = adjm[a];
    o_adj_sem[a] = wsi[W_MRK_SEM + a] ? old * 0.995f + 1.0f : old;
  }
}

extern "C" void kernel_launch(void* const* d_in, const int* in_sizes, int n_in,
                              void* d_out, int out_size, void* d_ws, size_t ws_size,
                              hipStream_t stream) {
  const float* zfre = (const float*)d_in[0];
  const float* zfim = (const float*)d_in[1];
  const float* zsre = (const float*)d_in[2];
  const float* zsim = (const float*)d_in[3];
  const float* cbs  = (const float*)d_in[4];
  const float* cbm  = (const float*)d_in[5];
  const float* Wsy  = (const float*)d_in[6];
  const float* bsy  = (const float*)d_in[7];
  const float* Wse  = (const float*)d_in[8];
  const float* bse  = (const float*)d_in[9];
  const float* clsi = (const float*)d_in[10];
  const float* avgs = (const float*)d_in[11];
  const float* clmi = (const float*)d_in[12];
  const float* avgm = (const float*)d_in[13];
  const float* adjs = (const float*)d_in[14];
  const float* adjm = (const float*)d_in[15];
  const int*   prvs = (const int*)d_in[16];
  const int*   prvm = (const int*)d_in[17];

  float* out = (float*)d_out;
  float* wsf = (float*)d_ws;
  int*   wsi = (int*)d_ws;
  _Float16* wsh = (_Float16*)d_ws;

  k_prep<<<849, 256, 0, stream>>>(cbs, cbm, Wsy, Wse, wsf,
      wsh + 2 * W_PACK_SYN, wsh + 2 * W_PACK_SEM);

  k_passA<64><<<N_TOK / 128, 256, 0, stream>>>(
      zfre, zfim, wsh + 2 * W_PACK_SYN, wsf + W_CBN_SYN, cbs, bsy, adjs, prvs,
      out + OFF_ZQ_SYN, out + OFF_IDX_SYN, wsi + W_IDX_SYN, wsi + W_MRK_SYN,
      wsf + W_LOSSP_SYN);
  k_passA<128><<<N_TOK / 128, 256, 0, stream>>>(
      zsre, zsim, wsh + 2 * W_PACK_SEM, wsf + W_CBN_SEM, cbm, bse, adjm, prvm,
      out + OFF_ZQ_SEM, out + OFF_IDX_SEM, wsi + W_IDX_SEM, wsi + W_MRK_SEM,
      wsf + W_LOSSP_SEM);

  k_passB_all<<<1024, 256, 0, stream>>>(
      zfre, zfim, zsre, zsim,
      wsi + W_IDX_SYN, wsi + W_IDX_SEM,
      wsf + W_EMB_SYN, wsf + W_EMB_SEM,
      wsi + W_CNT_SYN, wsi + W_CNT_SEM);

  k_fin<<<273, 256, 0, stream>>>(wsf, clsi, clmi, avgs, avgm, adjs, adjm,
      out + OFF_LOSS, out + OFF_CL_SYN, out + OFF_CL_SEM,
      out + OFF_CB_SYN, out + OFF_AVG_SYN, out + OFF_ADJ_SYN,
      out + OFF_CB_SEM, out + OFF_AVG_SEM, out + OFF_ADJ_SEM);
}

// Round 13
// 543.039 us; speedup vs baseline: 1.0349x; 1.0349x over previous
//
#include <hip/hip_runtime.h>

#define N_TOK 262144
#define LATD  128
#define DIMD  256

using f32x4  = __attribute__((ext_vector_type(4)))  float;
using f32x16 = __attribute__((ext_vector_type(16))) float;
using f16x8  = __attribute__((ext_vector_type(8)))  _Float16;
using f16x2  = __attribute__((ext_vector_type(2)))  _Float16;

// ---------------- workspace layout (32-bit word offsets) ----------------
#define W_PACK_SYN 0         // 65536 f16 (32768 words)
#define W_PACK_SEM 32768     // 131072 f16 (65536 words)
#define W_CBN_SYN  98304     // 64  f32 ||cb||^2
#define W_CBN_SEM  98368     // 128 f32
#define W_IDX_SYN  98496     // 262144 i32
#define W_IDX_SEM  360640    // 262144 i32
#define W_CNT_SYN  622784    // 64  i32
#define W_CNT_SEM  622848    // 128 i32
#define W_EMB_SYN  622976    // 64x256 f32
#define W_EMB_SEM  639360    // 128x256 f32
#define W_MRK_SYN  672128    // 64x64 i32
#define W_MRK_SEM  676224    // 128x128 i32
#define W_LOSSP_SYN 692612   // 2048 f32 per-block loss partials
#define W_LOSSP_SEM 700804   // 2048 f32
#define W_ZERO_BEG 622784
#define W_ZERO_END 692612

// ---------------- output layout (float offsets) ----------------
#define OFF_ZQ_SYN  0LL
#define OFF_ZQ_SEM  67108864LL
#define OFF_LOSS    134217728LL
#define OFF_IDX_SYN 134217729LL
#define OFF_IDX_SEM 134479873LL
#define OFF_CB_SYN  134742017LL
#define OFF_CL_SYN  134758401LL
#define OFF_AVG_SYN 134758465LL
#define OFF_ADJ_SYN 134774849LL
#define OFF_CB_SEM  134778945LL
#define OFF_CL_SEM  134811713LL
#define OFF_AVG_SEM 134811841LL
#define OFF_ADJ_SEM 134844609LL

__device__ inline void gload16(const void* g, void* l) {
  __builtin_amdgcn_global_load_lds(
      (const __attribute__((address_space(1))) unsigned int*)g,
      (__attribute__((address_space(3))) unsigned int*)l, 16, 0, 0);
}

// ==================== prep: zero + pack(syn,sem) + norms ====================
template <int K>
__device__ void prep_pack_body(int bid2, const float* __restrict__ cb,
                               const float* __restrict__ W, _Float16* __restrict__ pack) {
  constexpr int NCT = 2 * K / 32;
  constexpr int PER_KT = NCT * 512;
  int t = bid2 * 256 + threadIdx.x;
  int kt = t / PER_KT;
  int r  = t - kt * PER_KT;
  int l  = (r >> 3) & 63;
  int e  = r & 7;
  int ct = r >> 9;
  int j   = kt * 16 + (l >> 5) * 8 + e;
  int col = ct * 32 + (l & 31);
  float x = (col < K) ? cb[col * DIMD + j] : W[j * K + (col - K)];
  _Float16 h = (_Float16)x;
  _Float16 lo = (_Float16)(x - (float)h);
  pack[(size_t)kt * 2 * PER_KT + r]          = h;
  pack[(size_t)kt * 2 * PER_KT + PER_KT + r] = lo;
}

__global__ __launch_bounds__(256) void k_prep(
    const float* __restrict__ cbs, const float* __restrict__ cbm,
    const float* __restrict__ Wsy, const float* __restrict__ Wse,
    float* __restrict__ ws, _Float16* __restrict__ packs, _Float16* __restrict__ packm) {
  __shared__ float red[256];
  const int bid = blockIdx.x, tid = threadIdx.x;
  if (bid < 273) {
    int idx = W_ZERO_BEG + bid * 256 + tid;
    if (idx < W_ZERO_END) ws[idx] = 0.0f;
  } else if (bid < 401) {
    prep_pack_body<64>(bid - 273, cbs, Wsy, packs);
  } else if (bid < 657) {
    prep_pack_body<128>(bid - 401, cbm, Wse, packm);
  } else {
    int k = bid - 657;
    const float* src; float* dst;
    if (k < 64) { src = cbs + (size_t)k * DIMD; dst = ws + W_CBN_SYN + k; }
    else        { src = cbm + (size_t)(k - 64) * DIMD; dst = ws + W_CBN_SEM + (k - 64); }
    float v = src[tid];
    red[tid] = v * v;
    __syncthreads();
    for (int s = 128; s > 0; s >>= 1) {
      if (tid < s) red[tid] += red[tid + s];
      __syncthreads();
    }
    if (tid == 0) *dst = red[0];
  }
}

// ==================== pass A: LDS-staged pack, swapped-operand MFMA ====================
// Wave owns 32 tokens x all 2K entry rows.  Pack chunk (hi+lo) for kt is
// staged into LDS (double-buffered) via global_load_lds shared by 4 waves;
// one barrier per kt; z register-prefetched one kt ahead (issued first so
// the z loads are oldest in the vmem queue).  Epilogue register-local.
// syn runs 3 blocks/CU (z-latency-bound; more in-flight bytes), sem 2.
template <int K>
__global__ __launch_bounds__(256, (K == 64) ? 3 : 2) void k_passA(
    const float* __restrict__ zre, const float* __restrict__ zim,
    const _Float16* __restrict__ pack, const float* __restrict__ cbn,
    const float* __restrict__ cb,  const float* __restrict__ bvec,
    const float* __restrict__ adj, const int* __restrict__ prev,
    float* __restrict__ zq_out, float* __restrict__ idxf_out,
    int* __restrict__ idxi_ws, int* __restrict__ mark_ws,
    float* __restrict__ lossp) {
  constexpr int NCT = K / 16;             // 32-row tiles: 4 / 8
  constexpr int NH  = K / 32;             // 2 / 4
  constexpr int PER_KT = NCT * 512;       // f16 per hi (or lo) chunk
  constexpr int CHUNK = 2 * PER_KT;       // f16 per kt (hi+lo): 4096 / 8192
  constexpr int SITERS = CHUNK * 2 / 4096;  // pack 16B iters/thread: 2 / 4
  __shared__ __align__(16) _Float16 packl[2 * CHUNK];  // 16 KB / 32 KB
  __shared__ float wred[4];

  const int tid  = threadIdx.x;
  const int lane = tid & 63;
  const int wv   = tid >> 6;
  const int kg   = lane >> 5;
  const int j    = lane & 31;
  const int t0   = blockIdx.x * 128 + wv * 32;
  const int gt   = t0 + j;

  auto stage = [&](int kt) {
    const _Float16* src = pack + (size_t)kt * CHUNK;
    char* dst = (char*)packl + (kt & 1) * CHUNK * 2;
#pragma unroll
    for (int i = 0; i < SITERS; ++i)
      gload16(src + (size_t)(i * 256 + tid) * 8,
              dst + ((i * 256 + (tid & 192)) << 4));
  };

  f32x16 acc[NCT];
#pragma unroll
  for (int t = 0; t < NCT; ++t)
#pragma unroll
    for (int r = 0; r < 16; ++r) acc[t][r] = 0.0f;
  float zn = 0.0f;

  stage(0);
  f32x4 v0, v1, nv0, nv1;
  {
    const float* zp = zre + (size_t)gt * LATD + kg * 8;
    v0 = *(const f32x4*)zp;
    v1 = *(const f32x4*)(zp + 4);
  }
  for (int kt = 0; kt < 16; ++kt) {
    __syncthreads();                    // stage(kt) resident; buf^1 free
    if (kt + 1 < 16) {                  // z prefetch first: oldest in queue
      const float* zsrc2 = (kt + 1 < 8) ? zre : zim;
      const float* zp2 = zsrc2 + (size_t)gt * LATD + ((kt + 1) & 7) * 16 + kg * 8;
      nv0 = *(const f32x4*)zp2;
      nv1 = *(const f32x4*)(zp2 + 4);
      stage(kt + 1);
    }
    f16x8 Bh, Bl;
#pragma unroll
    for (int e = 0; e < 4; ++e) {
      _Float16 h0 = (_Float16)v0[e];
      Bh[e] = h0;       Bl[e] = (_Float16)(v0[e] - (float)h0);
      _Float16 h1 = (_Float16)v1[e];
      Bh[e + 4] = h1;   Bl[e + 4] = (_Float16)(v1[e] - (float)h1);
      zn += v0[e] * v0[e];
      zn += v1[e] * v1[e];
    }
    const _Float16* Bp = packl + (kt & 1) * CHUNK;
#pragma unroll
    for (int t = 0; t < NCT; ++t) {
      f16x8 Ah = *(const f16x8*)(Bp + (size_t)t * 512 + lane * 8);
      f16x8 Al = *(const f16x8*)(Bp + PER_KT + (size_t)t * 512 + lane * 8);
      acc[t] = __builtin_amdgcn_mfma_f32_32x32x16_f16(Ah, Bh, acc[t], 0, 0, 0);
      acc[t] = __builtin_amdgcn_mfma_f32_32x32x16_f16(Ah, Bl, acc[t], 0, 0, 0);
      acc[t] = __builtin_amdgcn_mfma_f32_32x32x16_f16(Al, Bh, acc[t], 0, 0, 0);
    }
    v0 = nv0; v1 = nv1;
  }

  const int pv = prev[gt];

  // softmax over logit tiles (in-register)
  float mx = -1e30f;
#pragma unroll
  for (int t = 0; t < NH; ++t)
#pragma unroll
    for (int q = 0; q < 4; ++q) {
      f32x4 bv4 = *(const f32x4*)&bvec[t * 32 + 8 * q + 4 * kg];
#pragma unroll
      for (int b = 0; b < 4; ++b) {
        acc[NH + t][4 * q + b] += bv4[b];
        mx = fmaxf(mx, acc[NH + t][4 * q + b]);
      }
    }
  mx = fmaxf(mx, __shfl_xor(mx, 32));
  float es = 0.0f;
#pragma unroll
  for (int t = 0; t < NH; ++t)
#pragma unroll
    for (int r = 0; r < 16; ++r) {
      acc[NH + t][r] = __expf(acc[NH + t][r] - mx);
      es += acc[NH + t][r];
    }
  es += __shfl_xor(es, 32);
  const float inv = 1.0f / es;

  // biased argmin as argmax of sc = dot - cbn/2 + 0.4 sg + p
  const float* adjrow = adj + (size_t)pv * K;
  float best = -1e30f; int bidx = 0; float bdot = 0.0f;
#pragma unroll
  for (int t = 0; t < NH; ++t)
#pragma unroll
    for (int q = 0; q < 4; ++q) {
      const int e0 = t * 32 + 8 * q + 4 * kg;
      f32x4 cb4v = *(const f32x4*)&cbn[e0];
      f32x4 ad4  = *(const f32x4*)&adjrow[e0];
#pragma unroll
      for (int b = 0; b < 4; ++b) {
        int r = 4 * q + b;
        float dot = acc[t][r];
        float sg  = 1.0f / (1.0f + __expf(-ad4[b]));
        float sc  = dot - 0.5f * cb4v[b] + 0.4f * sg + acc[NH + t][r] * inv;
        int   e   = e0 + b;
        if (sc > best || (sc == best && e < bidx)) {
          best = sc; bidx = e; bdot = dot;
        }
      }
    }
  {
    float ob = __shfl_xor(best, 32);
    int   oi = __shfl_xor(bidx, 32);
    float od = __shfl_xor(bdot, 32);
    if (ob > best || (ob == best && oi < bidx)) { best = ob; bidx = oi; bdot = od; }
  }
  const float znf = zn + __shfl_xor(zn, 32);

  float lj = 0.0f;
  if (lane < 32) {
    idxf_out[gt] = (float)bidx;
    idxi_ws[gt]  = bidx;
    mark_ws[pv * K + bidx] = 1;
    lj = cbn[bidx] + znf - 2.0f * bdot;
  }
#pragma unroll
  for (int off = 32; off; off >>= 1) lj += __shfl_xor(lj, off);
  if (lane == 0) wred[wv] = lj;

  // zq gather-write
  const float4* cb4p = (const float4*)cb;
  float4* zq4 = (float4*)zq_out;
#pragma unroll 4
  for (int i = 0; i < 32; ++i) {
    int bi_i = __shfl(bidx, i);
    zq4[(size_t)(t0 + i) * 64 + lane] = cb4p[(size_t)bi_i * 64 + lane];
  }
  __syncthreads();
  if (tid == 0) lossp[blockIdx.x] = wred[0] + wred[1] + wred[2] + wred[3];
}

// ==================== pass B (merged, interleaved, dbuf zT) ====================
template <int K>
__device__ void passB_body(int fid,
    const float* __restrict__ zre, const float* __restrict__ zim,
    const int* __restrict__ idxi,
    float* __restrict__ emb_ws, int* __restrict__ cnt_ws,
    int* idxl, int* cntl, unsigned short* zT) {
  constexpr int TPB  = 2048;
  constexpr int CH   = 128;
  constexpr int NCT2 = (K == 64) ? 1 : 2;
  const int tid  = threadIdx.x;
  const int lane = tid & 63, wv = tid >> 6;
  const int cg    = fid & 3;
  const int chunk = fid >> 2;
  const int tbase = chunk * TPB;

  if (tid < K) cntl[tid] = 0;
  __syncthreads();
#pragma unroll
  for (int i = 0; i < TPB / 256; ++i) {
    int id = idxi[tbase + i * 256 + tid];
    idxl[i * 256 + tid] = id;
    if (cg == 0) atomicAdd(&cntl[id], 1);
  }
  __syncthreads();
  if (cg == 0 && tid < K) atomicAdd(&cnt_ws[tid], cntl[tid]);

  const int rt  = (K == 64) ? (wv & 1) : wv;
  const int ct0 = (K == 64) ? (wv >> 1) : 0;
  const int krow = rt * 32 + (lane & 31);
  const int kg   = lane >> 5;
  const float* zsrc = (cg < 2) ? zre : zim;
  const int cbase = (cg & 1) * 64;

  f32x16 acc[NCT2];
#pragma unroll
  for (int c = 0; c < NCT2; ++c)
#pragma unroll
    for (int r = 0; r < 16; ++r) acc[c][r] = 0.0f;

  const int sq = tid & 15;
  const int sp = tid >> 4;

  auto stage = [&](int sc) {
    unsigned short* zb = zT + (sc & 1) * 8192;
#pragma unroll
    for (int it = 0; it < 4; ++it) {
      int p = sp + it * 16;
      int t = sc * CH + 2 * p;
      const float* zr = zsrc + (size_t)(tbase + t) * LATD + cbase + 4 * sq;
      f32x4 a = *(const f32x4*)zr;
      f32x4 b = *(const f32x4*)(zr + LATD);
#pragma unroll
      for (int c4 = 0; c4 < 4; ++c4) {
        int c = 4 * sq + c4;
        f16x2 pr;
        pr[0] = (_Float16)a[c4];
        pr[1] = (_Float16)b[c4];
        int byte = c * 256 + ((4 * p) ^ ((c & 7) << 4));
        *(f16x2*)((char*)zb + byte) = pr;
      }
    }
  };

  stage(0);
  for (int sc = 0; sc < TPB / CH; ++sc) {
    __syncthreads();
    if (sc + 1 < TPB / CH) stage(sc + 1);
    const unsigned short* zb = zT + (sc & 1) * 8192;
#pragma unroll
    for (int st = 0; st < 8; ++st) {
      const int tloc = sc * CH + st * 16 + kg * 8;
      f16x8 Af;
#pragma unroll
      for (int e = 0; e < 8; ++e)
        Af[e] = (idxl[tloc + e] == krow) ? (_Float16)1.0f : (_Float16)0.0f;
#pragma unroll
      for (int c = 0; c < NCT2; ++c) {
        int col = (ct0 + c) * 32 + (lane & 31);
        int byte = col * 256 + ((st * 32 + kg * 16) ^ ((col & 7) << 4));
        f16x8 Bf = *(const f16x8*)((const char*)zb + byte);
        acc[c] = __builtin_amdgcn_mfma_f32_32x32x16_f16(Af, Bf, acc[c], 0, 0, 0);
      }
    }
  }
#pragma unroll
  for (int c = 0; c < NCT2; ++c)
#pragma unroll
    for (int r = 0; r < 16; ++r) {
      int row = rt * 32 + (r & 3) + 8 * (r >> 2) + 4 * (lane >> 5);
      int col = cg * 64 + (ct0 + c) * 32 + (lane & 31);
      atomicAdd(&emb_ws[row * DIMD + col], acc[c][r]);
    }
}

__global__ __launch_bounds__(256) void k_passB_all(
    const float* __restrict__ zfre, const float* __restrict__ zfim,
    const float* __restrict__ zsre, const float* __restrict__ zsim,
    const int* __restrict__ idxis, const int* __restrict__ idxim,
    float* __restrict__ embs, float* __restrict__ embm,
    int* __restrict__ cnts, int* __restrict__ cntm) {
  __shared__ int idxl[2048];
  __shared__ int cntl[128];
  __shared__ __align__(16) unsigned short zT[2 * 8192];
  const int fid = blockIdx.x >> 1;
  if ((blockIdx.x & 1) == 0)
    passB_body<64>(fid, zfre, zfim, idxis, embs, cnts, idxl, cntl, zT);
  else
    passB_body<128>(fid, zsre, zsim, idxim, embm, cntm, idxl, cntl, zT);
}

// ==================== finalize (merged) ====================
__global__ __launch_bounds__(256) void k_fin(
    const float* __restrict__ ws, const float* __restrict__ clsi, const float* __restrict__ clmi,
    const float* __restrict__ avgs, const float* __restrict__ avgm,
    const float* __restrict__ adjs, const float* __restrict__ adjm,
    float* __restrict__ o_loss, float* __restrict__ o_cl_syn, float* __restrict__ o_cl_sem,
    float* __restrict__ o_cb_syn, float* __restrict__ o_avg_syn, float* __restrict__ o_adj_syn,
    float* __restrict__ o_cb_sem, float* __restrict__ o_avg_sem, float* __restrict__ o_adj_sem) {
  __shared__ float sred[256];
  const int* wsi = (const int*)ws;
  const int bid = blockIdx.x, tid = threadIdx.x;
  if (bid == 0) {
    float s = 0.0f;
    for (int i = tid; i < 2048; i += 256) s += ws[W_LOSSP_SYN + i];
    for (int i = tid; i < 2048; i += 256) s += ws[W_LOSSP_SEM + i];
    sred[tid] = s;
    __syncthreads();
    for (int st = 128; st > 0; st >>= 1) {
      if (tid < st) sred[tid] += sred[tid + st];
      __syncthreads();
    }
    if (tid < 64)
      o_cl_syn[tid] = clsi[tid] * 0.99f + 0.01f * (float)wsi[W_CNT_SYN + tid];
    if (tid < 128)
      o_cl_sem[tid] = clmi[tid] * 0.99f + 0.01f * (float)wsi[W_CNT_SEM + tid];
    if (tid == 0)
      *o_loss = 1.25f * sred[0] / ((float)N_TOK * 256.0f);
    return;
  }
  const int e = (bid - 1) * 256 + tid;
  float n = 0.0f;
  if (e < 49152) {
    const bool syn = e < 16384;
    const int KK = syn ? 64 : 128;
    const float* clp = syn ? clsi : clmi;
    const int cntoff = syn ? W_CNT_SYN : W_CNT_SEM;
    float v = 0.0f;
    if (tid < KK) v = clp[tid] * 0.99f + 0.01f * (float)wsi[cntoff + tid];
    sred[tid] = v;
    __syncthreads();
    for (int st = 128; st > 0; st >>= 1) {
      if (tid < st) sred[tid] += sred[tid + st];
      __syncthreads();
    }
    n = sred[0];
  }
  if (e < 16384) {
    int k = e >> 8;
    float av = avgs[e] * 0.99f + 0.01f * ws[W_EMB_SYN + e];
    o_avg_syn[e] = av;
    float cnt = (float)wsi[W_CNT_SYN + k];
    float cl  = clsi[k] * 0.99f + 0.01f * cnt;
    float cs  = (cl + 1e-6f) / (n + (float)(64 * 1e-6)) * n;
    o_cb_syn[e] = av / cs;
  } else if (e < 49152) {
    int e2 = e - 16384;
    int k = e2 >> 8;
    float av = avgm[e2] * 0.99f + 0.01f * ws[W_EMB_SEM + e2];
    o_avg_sem[e2] = av;
    float cnt = (float)wsi[W_CNT_SEM + k];
    float cl  = clmi[k] * 0.99f + 0.01f * cnt;
    float cs  = (cl + 1e-6f) / (n + (float)(128 * 1e-6)) * n;
    o_cb_sem[e2] = av / cs;
  } else if (e < 53248) {
    int a = e - 49152;
    float old = adjs[a];
    o_adj_syn[a] = wsi[W_MRK_SYN + a] ? old * 0.995f + 1.0f : old;
  } else if (e < 69632) {
    int a = e - 53248;
    float old = adjm[a];
    o_adj_sem[a] = wsi[W_MRK_SEM + a] ? old * 0.995f + 1.0f : old;
  }
}

extern "C" void kernel_launch(void* const* d_in, const int* in_sizes, int n_in,
                              void* d_out, int out_size, void* d_ws, size_t ws_size,
                              hipStream_t stream) {
  const float* zfre = (const float*)d_in[0];
  const float* zfim = (const float*)d_in[1];
  const float* zsre = (const float*)d_in[2];
  const float* zsim = (const float*)d_in[3];
  const float* cbs  = (const float*)d_in[4];
  const float* cbm  = (const float*)d_in[5];
  const float* Wsy  = (const float*)d_in[6];
  const float* bsy  = (const float*)d_in[7];
  const float* Wse  = (const float*)d_in[8];
  const float* bse  = (const float*)d_in[9];
  const float* clsi = (const float*)d_in[10];
  const float* avgs = (const float*)d_in[11];
  const float* clmi = (const float*)d_in[12];
  const float* avgm = (const float*)d_in[13];
  const float* adjs = (const float*)d_in[14];
  const float* adjm = (const float*)d_in[15];
  const int*   prvs = (const int*)d_in[16];
  const int*   prvm = (const int*)d_in[17];

  float* out = (float*)d_out;
  float* wsf = (float*)d_ws;
  int*   wsi = (int*)d_ws;
  _Float16* wsh = (_Float16*)d_ws;

  k_prep<<<849, 256, 0, stream>>>(cbs, cbm, Wsy, Wse, wsf,
      wsh + 2 * W_PACK_SYN, wsh + 2 * W_PACK_SEM);

  k_passA<64><<<N_TOK / 128, 256, 0, stream>>>(
      zfre, zfim, wsh + 2 * W_PACK_SYN, wsf + W_CBN_SYN, cbs, bsy, adjs, prvs,
      out + OFF_ZQ_SYN, out + OFF_IDX_SYN, wsi + W_IDX_SYN, wsi + W_MRK_SYN,
      wsf + W_LOSSP_SYN);
  k_passA<128><<<N_TOK / 128, 256, 0, stream>>>(
      zsre, zsim, wsh + 2 * W_PACK_SEM, wsf + W_CBN_SEM, cbm, bse, adjm, prvm,
      out + OFF_ZQ_SEM, out + OFF_IDX_SEM, wsi + W_IDX_SEM, wsi + W_MRK_SEM,
      wsf + W_LOSSP_SEM);

  k_passB_all<<<1024, 256, 0, stream>>>(
      zfre, zfim, zsre, zsim,
      wsi + W_IDX_SYN, wsi + W_IDX_SEM,
      wsf + W_EMB_SYN, wsf + W_EMB_SEM,
      wsi + W_CNT_SYN, wsi + W_CNT_SEM);

  k_fin<<<273, 256, 0, stream>>>(wsf, clsi, clmi, avgs, avgm, adjs, adjm,
      out + OFF_LOSS, out + OFF_CL_SYN, out + OFF_CL_SEM,
      out + OFF_CB_SYN, out + OFF_AVG_SYN, out + OFF_ADJ_SYN,
      out + OFF_CB_SEM, out + OFF_AVG_SEM, out + OFF_ADJ_SEM);
}

// Round 14
// 503.109 us; speedup vs baseline: 1.1170x; 1.0794x over previous
//
#include <hip/hip_runtime.h>

#define N_TOK 262144
#define LATD  128
#define DIMD  256

using f32x4  = __attribute__((ext_vector_type(4)))  float;
using f32x16 = __attribute__((ext_vector_type(16))) float;
using f16x8  = __attribute__((ext_vector_type(8)))  _Float16;
using f16x2  = __attribute__((ext_vector_type(2)))  _Float16;

// ---------------- workspace layout (32-bit word offsets) ----------------
#define W_PACK_SYN 0         // 65536 f16 (32768 words)
#define W_PACK_SEM 32768     // 131072 f16 (65536 words)
#define W_CBN_SYN  98304     // 64  f32 ||cb||^2
#define W_CBN_SEM  98368     // 128 f32
#define W_IDX_SYN  98496     // 262144 i32
#define W_IDX_SEM  360640    // 262144 i32
#define W_CNT_SYN  622784    // 64  i32
#define W_CNT_SEM  622848    // 128 i32
#define W_EMB_SYN  622976    // 64x256 f32
#define W_EMB_SEM  639360    // 128x256 f32
#define W_MRK_SYN  672128    // 64x64 i32
#define W_MRK_SEM  676224    // 128x128 i32
#define W_LOSSP_SYN 692612   // 2048 f32 per-block loss partials
#define W_LOSSP_SEM 700804   // 2048 f32
#define W_ZERO_BEG 622784
#define W_ZERO_END 692612

// ---------------- output layout (float offsets) ----------------
#define OFF_ZQ_SYN  0LL
#define OFF_ZQ_SEM  67108864LL
#define OFF_LOSS    134217728LL
#define OFF_IDX_SYN 134217729LL
#define OFF_IDX_SEM 134479873LL
#define OFF_CB_SYN  134742017LL
#define OFF_CL_SYN  134758401LL
#define OFF_AVG_SYN 134758465LL
#define OFF_ADJ_SYN 134774849LL
#define OFF_CB_SEM  134778945LL
#define OFF_CL_SEM  134811713LL
#define OFF_AVG_SEM 134811841LL
#define OFF_ADJ_SEM 134844609LL

__device__ inline void gload16(const void* g, void* l) {
  __builtin_amdgcn_global_load_lds(
      (const __attribute__((address_space(1))) unsigned int*)g,
      (__attribute__((address_space(3))) unsigned int*)l, 16, 0, 0);
}

// ==================== prep: zero + pack(syn,sem) + norms ====================
template <int K>
__device__ void prep_pack_body(int bid2, const float* __restrict__ cb,
                               const float* __restrict__ W, _Float16* __restrict__ pack) {
  constexpr int NCT = 2 * K / 32;
  constexpr int PER_KT = NCT * 512;
  int t = bid2 * 256 + threadIdx.x;
  int kt = t / PER_KT;
  int r  = t - kt * PER_KT;
  int l  = (r >> 3) & 63;
  int e  = r & 7;
  int ct = r >> 9;
  int j   = kt * 16 + (l >> 5) * 8 + e;
  int col = ct * 32 + (l & 31);
  float x = (col < K) ? cb[col * DIMD + j] : W[j * K + (col - K)];
  _Float16 h = (_Float16)x;
  _Float16 lo = (_Float16)(x - (float)h);
  pack[(size_t)kt * 2 * PER_KT + r]          = h;
  pack[(size_t)kt * 2 * PER_KT + PER_KT + r] = lo;
}

__global__ __launch_bounds__(256) void k_prep(
    const float* __restrict__ cbs, const float* __restrict__ cbm,
    const float* __restrict__ Wsy, const float* __restrict__ Wse,
    float* __restrict__ ws, _Float16* __restrict__ packs, _Float16* __restrict__ packm) {
  __shared__ float red[256];
  const int bid = blockIdx.x, tid = threadIdx.x;
  if (bid < 273) {
    int idx = W_ZERO_BEG + bid * 256 + tid;
    if (idx < W_ZERO_END) ws[idx] = 0.0f;
  } else if (bid < 401) {
    prep_pack_body<64>(bid - 273, cbs, Wsy, packs);
  } else if (bid < 657) {
    prep_pack_body<128>(bid - 401, cbm, Wse, packm);
  } else {
    int k = bid - 657;
    const float* src; float* dst;
    if (k < 64) { src = cbs + (size_t)k * DIMD; dst = ws + W_CBN_SYN + k; }
    else        { src = cbm + (size_t)(k - 64) * DIMD; dst = ws + W_CBN_SEM + (k - 64); }
    float v = src[tid];
    red[tid] = v * v;
    __syncthreads();
    for (int s = 128; s > 0; s >>= 1) {
      if (tid < s) red[tid] += red[tid + s];
      __syncthreads();
    }
    if (tid == 0) *dst = red[0];
  }
}

// ==================== pass A: LDS-staged pack, swapped-operand MFMA ====================
// Wave owns 32 tokens x all 2K entry rows.  Pack chunk (hi+lo) for kt is
// staged into LDS (double-buffered) via global_load_lds shared by 4 waves;
// one barrier per kt; stage(kt+1) issued right after the barrier so loads
// stay in flight under compute.  z register-prefetched.  Epilogue register-local.
template <int K>
__global__ __launch_bounds__(256, 2) void k_passA(
    const float* __restrict__ zre, const float* __restrict__ zim,
    const _Float16* __restrict__ pack, const float* __restrict__ cbn,
    const float* __restrict__ cb,  const float* __restrict__ bvec,
    const float* __restrict__ adj, const int* __restrict__ prev,
    float* __restrict__ zq_out, float* __restrict__ idxf_out,
    int* __restrict__ idxi_ws, int* __restrict__ mark_ws,
    float* __restrict__ lossp) {
  constexpr int NCT = K / 16;             // 32-row tiles: 4 / 8
  constexpr int NH  = K / 32;             // 2 / 4
  constexpr int PER_KT = NCT * 512;       // f16 per hi (or lo) chunk
  constexpr int CHUNK = 2 * PER_KT;       // f16 per kt (hi+lo): 4096 / 8192
  constexpr int SITERS = CHUNK * 2 / 4096;  // pack 16B iters/thread: 2 / 4
  __shared__ __align__(16) _Float16 packl[2 * CHUNK];  // 16 KB / 32 KB
  __shared__ float wred[4];

  const int tid  = threadIdx.x;
  const int lane = tid & 63;
  const int wv   = tid >> 6;
  const int kg   = lane >> 5;
  const int j    = lane & 31;
  const int t0   = blockIdx.x * 128 + wv * 32;
  const int gt   = t0 + j;

  auto stage = [&](int kt) {
    const _Float16* src = pack + (size_t)kt * CHUNK;
    char* dst = (char*)packl + (kt & 1) * CHUNK * 2;
#pragma unroll
    for (int i = 0; i < SITERS; ++i)
      gload16(src + (size_t)(i * 256 + tid) * 8,
              dst + ((i * 256 + (tid & 192)) << 4));
  };

  f32x16 acc[NCT];
#pragma unroll
  for (int t = 0; t < NCT; ++t)
#pragma unroll
    for (int r = 0; r < 16; ++r) acc[t][r] = 0.0f;
  float zn = 0.0f;

  stage(0);
  f32x4 v0, v1, nv0, nv1;
  {
    const float* zp = zre + (size_t)gt * LATD + kg * 8;
    v0 = *(const f32x4*)zp;
    v1 = *(const f32x4*)(zp + 4);
  }
  for (int kt = 0; kt < 16; ++kt) {
    __syncthreads();                    // stage(kt) resident; buf^1 free
    if (kt + 1 < 16) stage(kt + 1);
    if (kt + 1 < 16) {
      const float* zsrc2 = (kt + 1 < 8) ? zre : zim;
      const float* zp2 = zsrc2 + (size_t)gt * LATD + ((kt + 1) & 7) * 16 + kg * 8;
      nv0 = *(const f32x4*)zp2;
      nv1 = *(const f32x4*)(zp2 + 4);
    }
    f16x8 Bh, Bl;
#pragma unroll
    for (int e = 0; e < 4; ++e) {
      _Float16 h0 = (_Float16)v0[e];
      Bh[e] = h0;       Bl[e] = (_Float16)(v0[e] - (float)h0);
      _Float16 h1 = (_Float16)v1[e];
      Bh[e + 4] = h1;   Bl[e + 4] = (_Float16)(v1[e] - (float)h1);
      zn += v0[e] * v0[e];
      zn += v1[e] * v1[e];
    }
    const _Float16* Bp = packl + (kt & 1) * CHUNK;
#pragma unroll
    for (int t = 0; t < NCT; ++t) {
      f16x8 Ah = *(const f16x8*)(Bp + (size_t)t * 512 + lane * 8);
      f16x8 Al = *(const f16x8*)(Bp + PER_KT + (size_t)t * 512 + lane * 8);
      acc[t] = __builtin_amdgcn_mfma_f32_32x32x16_f16(Ah, Bh, acc[t], 0, 0, 0);
      acc[t] = __builtin_amdgcn_mfma_f32_32x32x16_f16(Ah, Bl, acc[t], 0, 0, 0);
      acc[t] = __builtin_amdgcn_mfma_f32_32x32x16_f16(Al, Bh, acc[t], 0, 0, 0);
    }
    v0 = nv0; v1 = nv1;
  }

  const int pv = prev[gt];

  // softmax over logit tiles (in-register)
  float mx = -1e30f;
#pragma unroll
  for (int t = 0; t < NH; ++t)
#pragma unroll
    for (int q = 0; q < 4; ++q) {
      f32x4 bv4 = *(const f32x4*)&bvec[t * 32 + 8 * q + 4 * kg];
#pragma unroll
      for (int b = 0; b < 4; ++b) {
        acc[NH + t][4 * q + b] += bv4[b];
        mx = fmaxf(mx, acc[NH + t][4 * q + b]);
      }
    }
  mx = fmaxf(mx, __shfl_xor(mx, 32));
  float es = 0.0f;
#pragma unroll
  for (int t = 0; t < NH; ++t)
#pragma unroll
    for (int r = 0; r < 16; ++r) {
      acc[NH + t][r] = __expf(acc[NH + t][r] - mx);
      es += acc[NH + t][r];
    }
  es += __shfl_xor(es, 32);
  const float inv = 1.0f / es;

  // biased argmin as argmax of sc = dot - cbn/2 + 0.4 sg + p
  const float* adjrow = adj + (size_t)pv * K;
  float best = -1e30f; int bidx = 0; float bdot = 0.0f;
#pragma unroll
  for (int t = 0; t < NH; ++t)
#pragma unroll
    for (int q = 0; q < 4; ++q) {
      const int e0 = t * 32 + 8 * q + 4 * kg;
      f32x4 cb4v = *(const f32x4*)&cbn[e0];
      f32x4 ad4  = *(const f32x4*)&adjrow[e0];
#pragma unroll
      for (int b = 0; b < 4; ++b) {
        int r = 4 * q + b;
        float dot = acc[t][r];
        float sg  = 1.0f / (1.0f + __expf(-ad4[b]));
        float sc  = dot - 0.5f * cb4v[b] + 0.4f * sg + acc[NH + t][r] * inv;
        int   e   = e0 + b;
        if (sc > best || (sc == best && e < bidx)) {
          best = sc; bidx = e; bdot = dot;
        }
      }
    }
  {
    float ob = __shfl_xor(best, 32);
    int   oi = __shfl_xor(bidx, 32);
    float od = __shfl_xor(bdot, 32);
    if (ob > best || (ob == best && oi < bidx)) { best = ob; bidx = oi; bdot = od; }
  }
  const float znf = zn + __shfl_xor(zn, 32);

  float lj = 0.0f;
  if (lane < 32) {
    idxf_out[gt] = (float)bidx;
    idxi_ws[gt]  = bidx;
    mark_ws[pv * K + bidx] = 1;
    lj = cbn[bidx] + znf - 2.0f * bdot;
  }
#pragma unroll
  for (int off = 32; off; off >>= 1) lj += __shfl_xor(lj, off);
  if (lane == 0) wred[wv] = lj;

  // zq gather-write
  const float4* cb4p = (const float4*)cb;
  float4* zq4 = (float4*)zq_out;
#pragma unroll 4
  for (int i = 0; i < 32; ++i) {
    int bi_i = __shfl(bidx, i);
    zq4[(size_t)(t0 + i) * 64 + lane] = cb4p[(size_t)bi_i * 64 + lane];
  }
  __syncthreads();
  if (tid == 0) lossp[blockIdx.x] = wred[0] + wred[1] + wred[2] + wred[3];
}

// ==================== pass B (merged, interleaved, dbuf zT) ====================
template <int K>
__device__ void passB_body(int fid,
    const float* __restrict__ zre, const float* __restrict__ zim,
    const int* __restrict__ idxi,
    float* __restrict__ emb_ws, int* __restrict__ cnt_ws,
    int* idxl, int* cntl, unsigned short* zT) {
  constexpr int TPB  = 2048;
  constexpr int CH   = 128;
  constexpr int NCT2 = (K == 64) ? 1 : 2;
  const int tid  = threadIdx.x;
  const int lane = tid & 63, wv = tid >> 6;
  const int cg    = fid & 3;
  const int chunk = fid >> 2;
  const int tbase = chunk * TPB;

  if (tid < K) cntl[tid] = 0;
  __syncthreads();
#pragma unroll
  for (int i = 0; i < TPB / 256; ++i) {
    int id = idxi[tbase + i * 256 + tid];
    idxl[i * 256 + tid] = id;
    if (cg == 0) atomicAdd(&cntl[id], 1);
  }
  __syncthreads();
  if (cg == 0 && tid < K) atomicAdd(&cnt_ws[tid], cntl[tid]);

  const int rt  = (K == 64) ? (wv & 1) : wv;
  const int ct0 = (K == 64) ? (wv >> 1) : 0;
  const int krow = rt * 32 + (lane & 31);
  const int kg   = lane >> 5;
  const float* zsrc = (cg < 2) ? zre : zim;
  const int cbase = (cg & 1) * 64;

  f32x16 acc[NCT2];
#pragma unroll
  for (int c = 0; c < NCT2; ++c)
#pragma unroll
    for (int r = 0; r < 16; ++r) acc[c][r] = 0.0f;

  const int sq = tid & 15;
  const int sp = tid >> 4;

  auto stage = [&](int sc) {
    unsigned short* zb = zT + (sc & 1) * 8192;
#pragma unroll
    for (int it = 0; it < 4; ++it) {
      int p = sp + it * 16;
      int t = sc * CH + 2 * p;
      const float* zr = zsrc + (size_t)(tbase + t) * LATD + cbase + 4 * sq;
      f32x4 a = *(const f32x4*)zr;
      f32x4 b = *(const f32x4*)(zr + LATD);
#pragma unroll
      for (int c4 = 0; c4 < 4; ++c4) {
        int c = 4 * sq + c4;
        f16x2 pr;
        pr[0] = (_Float16)a[c4];
        pr[1] = (_Float16)b[c4];
        int byte = c * 256 + ((4 * p) ^ ((c & 7) << 4));
        *(f16x2*)((char*)zb + byte) = pr;
      }
    }
  };

  stage(0);
  for (int sc = 0; sc < TPB / CH; ++sc) {
    __syncthreads();
    if (sc + 1 < TPB / CH) stage(sc + 1);
    const unsigned short* zb = zT + (sc & 1) * 8192;
#pragma unroll
    for (int st = 0; st < 8; ++st) {
      const int tloc = sc * CH + st * 16 + kg * 8;
      f16x8 Af;
#pragma unroll
      for (int e = 0; e < 8; ++e)
        Af[e] = (idxl[tloc + e] == krow) ? (_Float16)1.0f : (_Float16)0.0f;
#pragma unroll
      for (int c = 0; c < NCT2; ++c) {
        int col = (ct0 + c) * 32 + (lane & 31);
        int byte = col * 256 + ((st * 32 + kg * 16) ^ ((col & 7) << 4));
        f16x8 Bf = *(const f16x8*)((const char*)zb + byte);
        acc[c] = __builtin_amdgcn_mfma_f32_32x32x16_f16(Af, Bf, acc[c], 0, 0, 0);
      }
    }
  }
#pragma unroll
  for (int c = 0; c < NCT2; ++c)
#pragma unroll
    for (int r = 0; r < 16; ++r) {
      int row = rt * 32 + (r & 3) + 8 * (r >> 2) + 4 * (lane >> 5);
      int col = cg * 64 + (ct0 + c) * 32 + (lane & 31);
      atomicAdd(&emb_ws[row * DIMD + col], acc[c][r]);
    }
}

__global__ __launch_bounds__(256) void k_passB_all(
    const float* __restrict__ zfre, const float* __restrict__ zfim,
    const float* __restrict__ zsre, const float* __restrict__ zsim,
    const int* __restrict__ idxis, const int* __restrict__ idxim,
    float* __restrict__ embs, float* __restrict__ embm,
    int* __restrict__ cnts, int* __restrict__ cntm) {
  __shared__ int idxl[2048];
  __shared__ int cntl[128];
  __shared__ __align__(16) unsigned short zT[2 * 8192];
  const int fid = blockIdx.x >> 1;
  if ((blockIdx.x & 1) == 0)
    passB_body<64>(fid, zfre, zfim, idxis, embs, cnts, idxl, cntl, zT);
  else
    passB_body<128>(fid, zsre, zsim, idxim, embm, cntm, idxl, cntl, zT);
}

// ==================== finalize (merged) ====================
__global__ __launch_bounds__(256) void k_fin(
    const float* __restrict__ ws, const float* __restrict__ clsi, const float* __restrict__ clmi,
    const float* __restrict__ avgs, const float* __restrict__ avgm,
    const float* __restrict__ adjs, const float* __restrict__ adjm,
    float* __restrict__ o_loss, float* __restrict__ o_cl_syn, float* __restrict__ o_cl_sem,
    float* __restrict__ o_cb_syn, float* __restrict__ o_avg_syn, float* __restrict__ o_adj_syn,
    float* __restrict__ o_cb_sem, float* __restrict__ o_avg_sem, float* __restrict__ o_adj_sem) {
  __shared__ float sred[256];
  const int* wsi = (const int*)ws;
  const int bid = blockIdx.x, tid = threadIdx.x;
  if (bid == 0) {
    float s = 0.0f;
    for (int i = tid; i < 2048; i += 256) s += ws[W_LOSSP_SYN + i];
    for (int i = tid; i < 2048; i += 256) s += ws[W_LOSSP_SEM + i];
    sred[tid] = s;
    __syncthreads();
    for (int st = 128; st > 0; st >>= 1) {
      if (tid < st) sred[tid] += sred[tid + st];
      __syncthreads();
    }
    if (tid < 64)
      o_cl_syn[tid] = clsi[tid] * 0.99f + 0.01f * (float)wsi[W_CNT_SYN + tid];
    if (tid < 128)
      o_cl_sem[tid] = clmi[tid] * 0.99f + 0.01f * (float)wsi[W_CNT_SEM + tid];
    if (tid == 0)
      *o_loss = 1.25f * sred[0] / ((float)N_TOK * 256.0f);
    return;
  }
  const int e = (bid - 1) * 256 + tid;
  float n = 0.0f;
  if (e < 49152) {
    const bool syn = e < 16384;
    const int KK = syn ? 64 : 128;
    const float* clp = syn ? clsi : clmi;
    const int cntoff = syn ? W_CNT_SYN : W_CNT_SEM;
    float v = 0.0f;
    if (tid < KK) v = clp[tid] * 0.99f + 0.01f * (float)wsi[cntoff + tid];
    sred[tid] = v;
    __syncthreads();
    for (int st = 128; st > 0; st >>= 1) {
      if (tid < st) sred[tid] += sred[tid + st];
      __syncthreads();
    }
    n = sred[0];
  }
  if (e < 16384) {
    int k = e >> 8;
    float av = avgs[e] * 0.99f + 0.01f * ws[W_EMB_SYN + e];
    o_avg_syn[e] = av;
    float cnt = (float)wsi[W_CNT_SYN + k];
    float cl  = clsi[k] * 0.99f + 0.01f * cnt;
    float cs  = (cl + 1e-6f) / (n + (float)(64 * 1e-6)) * n;
    o_cb_syn[e] = av / cs;
  } else if (e < 49152) {
    int e2 = e - 16384;
    int k = e2 >> 8;
    float av = avgm[e2] * 0.99f + 0.01f * ws[W_EMB_SEM + e2];
    o_avg_sem[e2] = av;
    float cnt = (float)wsi[W_CNT_SEM + k];
    float cl  = clmi[k] * 0.99f + 0.01f * cnt;
    float cs  = (cl + 1e-6f) / (n + (float)(128 * 1e-6)) * n;
    o_cb_sem[e2] = av / cs;
  } else if (e < 53248) {
    int a = e - 49152;
    float old = adjs[a];
    o_adj_syn[a] = wsi[W_MRK_SYN + a] ? old * 0.995f + 1.0f : old;
  } else if (e < 69632) {
    int a = e - 53248;
    float old = adjm[a];
    o_adj_sem[a] = wsi[W_MRK_SEM + a] ? old * 0.995f + 1.0f : old;
  }
}

extern "C" void kernel_launch(void* const* d_in, const int* in_sizes, int n_in,
                              void* d_out, int out_size, void* d_ws, size_t ws_size,
                              hipStream_t stream) {
  const float* zfre = (const float*)d_in[0];
  const float* zfim = (const float*)d_in[1];
  const float* zsre = (const float*)d_in[2];
  const float* zsim = (const float*)d_in[3];
  const float* cbs  = (const float*)d_in[4];
  const float* cbm  = (const float*)d_in[5];
  const float* Wsy  = (const float*)d_in[6];
  const float* bsy  = (const float*)d_in[7];
  const float* Wse  = (const float*)d_in[8];
  const float* bse  = (const float*)d_in[9];
  const float* clsi = (const float*)d_in[10];
  const float* avgs = (const float*)d_in[11];
  const float* clmi = (const float*)d_in[12];
  const float* avgm = (const float*)d_in[13];
  const float* adjs = (const float*)d_in[14];
  const float* adjm = (const float*)d_in[15];
  const int*   prvs = (const int*)d_in[16];
  const int*   prvm = (const int*)d_in[17];

  float* out = (float*)d_out;
  float* wsf = (float*)d_ws;
  int*   wsi = (int*)d_ws;
  _Float16* wsh = (_Float16*)d_ws;

  k_prep<<<849, 256, 0, stream>>>(cbs, cbm, Wsy, Wse, wsf,
      wsh + 2 * W_PACK_SYN, wsh + 2 * W_PACK_SEM);

  k_passA<64><<<N_TOK / 128, 256, 0, stream>>>(
      zfre, zfim, wsh + 2 * W_PACK_SYN, wsf + W_CBN_SYN, cbs, bsy, adjs, prvs,
      out + OFF_ZQ_SYN, out + OFF_IDX_SYN, wsi + W_IDX_SYN, wsi + W_MRK_SYN,
      wsf + W_LOSSP_SYN);
  k_passA<128><<<N_TOK / 128, 256, 0, stream>>>(
      zsre, zsim, wsh + 2 * W_PACK_SEM, wsf + W_CBN_SEM, cbm, bse, adjm, prvm,
      out + OFF_ZQ_SEM, out + OFF_IDX_SEM, wsi + W_IDX_SEM, wsi + W_MRK_SEM,
      wsf + W_LOSSP_SEM);

  k_passB_all<<<1024, 256, 0, stream>>>(
      zfre, zfim, zsre, zsim,
      wsi + W_IDX_SYN, wsi + W_IDX_SEM,
      wsf + W_EMB_SYN, wsf + W_EMB_SEM,
      wsi + W_CNT_SYN, wsi + W_CNT_SEM);

  k_fin<<<273, 256, 0, stream>>>(wsf, clsi, clmi, avgs, avgm, adjs, adjm,
      out + OFF_LOSS, out + OFF_CL_SYN, out + OFF_CL_SEM,
      out + OFF_CB_SYN, out + OFF_AVG_SYN, out + OFF_ADJ_SYN,
      out + OFF_CB_SEM, out + OFF_AVG_SEM, out + OFF_ADJ_SEM);
}